// Round 2
// baseline (249.039 us; speedup 1.0000x reference)
//
#include <hip/hip_runtime.h>
#include <hip/hip_bf16.h>

#define SEQ  4096
#define HID  768
#define NH   12
#define HD   64
#define QKVN 2304

typedef __attribute__((ext_vector_type(8)))  short  short8;
typedef __attribute__((ext_vector_type(4)))  float  f32x4;
typedef __attribute__((ext_vector_type(16))) float  f32x16;

static __device__ __forceinline__ unsigned short bf16b(float x) {
  __hip_bfloat16 h = __float2bfloat16(x);
  return *reinterpret_cast<unsigned short*>(&h);
}
static __device__ __forceinline__ unsigned pkbf(float lo, float hi) {
  return (unsigned)bf16b(lo) | ((unsigned)bf16b(hi) << 16);
}
static __device__ __forceinline__ void store4(__hip_bfloat16* p, float a, float b, float c, float d) {
  unsigned long long v = (unsigned long long)pkbf(a, b) | ((unsigned long long)pkbf(c, d) << 32);
  *reinterpret_cast<unsigned long long*>(p) = v;
}
// async global->LDS, 16B per lane; LDS base wave-uniform, writes at base+lane*16 (m104/m108)
static __device__ __forceinline__ void gload16(const void* g, void* l) {
  __builtin_amdgcn_global_load_lds(
      (const __attribute__((address_space(1))) void*)g,
      (__attribute__((address_space(3))) void*)l, 16, 0, 0);
}

static __device__ __forceinline__ void cvt_store(float* p, float v) { *p = v; }
static __device__ __forceinline__ void cvt_store(__hip_bfloat16* p, float v) { *p = __float2bfloat16(v); }

// ---------------- prep: fp32 -> bf16 casts + weight/bias concat ----------------
__global__ __launch_bounds__(256) void prep_kernel(
    const float* __restrict__ hs,
    const float* __restrict__ qw, const float* __restrict__ kw,
    const float* __restrict__ vw, const float* __restrict__ ow,
    const float* __restrict__ qb, const float* __restrict__ kb,
    const float* __restrict__ vb,
    __hip_bfloat16* __restrict__ Xb,    // [SEQ][HID]
    __hip_bfloat16* __restrict__ Wqkv,  // [2304][768] rows = q,k,v weights
    __hip_bfloat16* __restrict__ Wo,    // [768][768]
    float* __restrict__ bqkv)           // [2304]
{
  const int NX = SEQ*HID/4, NW = QKVN*HID/4, NO = HID*HID/4, NB = QKVN/4;
  int idx = blockIdx.x*256 + threadIdx.x;
  if (idx < NX) {
    float4 v = ((const float4*)hs)[idx];
    store4(Xb + idx*4, v.x, v.y, v.z, v.w);
  } else if (idx < NX + NW) {
    int f = (idx - NX)*4;
    int row = f / HID, col = f - row*HID;
    const float* src = (row < HID)   ? qw + row*HID + col
                     : (row < 2*HID) ? kw + (row-HID)*HID + col
                     :                 vw + (row-2*HID)*HID + col;
    float4 v = *(const float4*)src;
    store4(Wqkv + f, v.x, v.y, v.z, v.w);
  } else if (idx < NX + NW + NO) {
    int li = idx - NX - NW;
    float4 v = ((const float4*)ow)[li];
    store4(Wo + li*4, v.x, v.y, v.z, v.w);
  } else if (idx < NX + NW + NO + NB) {
    int f = (idx - NX - NW - NO)*4;
    const float* src = (f < HID) ? qb + f : (f < 2*HID) ? kb + (f-HID) : vb + (f-2*HID);
    *(float4*)(bqkv + f) = *(const float4*)src;
  }
}

// ---------------- GEMM  C[M][N] = A[M][K] * B[N][K]^T + bias  (m97 structure) ----
template <typename OutT>
__global__ __launch_bounds__(256) void gemm_nt(
    const __hip_bfloat16* __restrict__ A,
    const __hip_bfloat16* __restrict__ B,
    const float* __restrict__ bias,
    OutT* __restrict__ C, int N, int K)
{
  __shared__ __align__(16) short As[128*32];
  __shared__ __align__(16) short Bs[128*32];
  const int tid  = threadIdx.x;
  const int lane = tid & 63;
  const int w    = tid >> 6;
  const int m0   = blockIdx.y * 128;
  const int n0   = blockIdx.x * 128;
  const int wrow = w >> 1, wcol = w & 1;
  const int l15  = lane & 15;
  const int k8   = (lane >> 4) * 8;

  f32x4 acc[4][4] = {};

  const int base0 = w*512;
  const int base1 = (4+w)*512;
  const int f0 = base0 + lane*8, f1 = base1 + lane*8;
  const __hip_bfloat16* Ap0 = A + (long)(m0 + (f0>>5))*K + (f0&31);
  const __hip_bfloat16* Ap1 = A + (long)(m0 + (f1>>5))*K + (f1&31);
  const __hip_bfloat16* Bp0 = B + (long)(n0 + (f0>>5))*K + (f0&31);
  const __hip_bfloat16* Bp1 = B + (long)(n0 + (f1>>5))*K + (f1&31);

  for (int k0 = 0; k0 < K; k0 += 32) {
    gload16(Ap0 + k0, As + base0);
    gload16(Ap1 + k0, As + base1);
    gload16(Bp0 + k0, Bs + base0);
    gload16(Bp1 + k0, Bs + base1);
    __syncthreads();

    short8 af[4], bfm[4];
#pragma unroll
    for (int mi = 0; mi < 4; ++mi)
      af[mi] = *(const short8*)&As[(wrow*64 + mi*16 + l15)*32 + k8];
#pragma unroll
    for (int ni = 0; ni < 4; ++ni)
      bfm[ni] = *(const short8*)&Bs[(wcol*64 + ni*16 + l15)*32 + k8];
#pragma unroll
    for (int mi = 0; mi < 4; ++mi)
#pragma unroll
      for (int ni = 0; ni < 4; ++ni)
        acc[mi][ni] = __builtin_amdgcn_mfma_f32_16x16x32_bf16(af[mi], bfm[ni], acc[mi][ni], 0, 0, 0);
    __syncthreads();
  }

  const int rbase = (lane >> 4) * 4;   // C/D: col = lane&15, row = (lane>>4)*4 + reg (m89)
#pragma unroll
  for (int mi = 0; mi < 4; ++mi)
#pragma unroll
    for (int ni = 0; ni < 4; ++ni) {
      int gm = m0 + wrow*64 + mi*16 + rbase;
      int gn = n0 + wcol*64 + ni*16 + l15;
      float bv = bias[gn];
#pragma unroll
      for (int r = 0; r < 4; ++r)
        cvt_store(&C[(long)(gm + r)*N + gn], acc[mi][ni][r] + bv);
    }
}

// ---------------- flash attention -------------------------------------------
// grid (SEQ/64, NH); 128 thr = 2 waves, each wave owns 32 q-rows; KV block 32.
// Swapped QK^T: S^T = mfma(K, Q^T) -> lane owns q-col (lane&31).
// PV: O^T = mfma(V^T, P^T); V^T built explicitly in LDS via transposed ds_write
// (conservative round: no ds_read_b64_tr_b16, no inline asm).
__global__ __launch_bounds__(128) void attn_fwd(
    const __hip_bfloat16* __restrict__ QKV,  // [SEQ][2304]
    const float* __restrict__ mask,          // [SEQ]
    __hip_bfloat16* __restrict__ ctx)        // [SEQ][768]
{
  __shared__ __align__(16) short Ks[32*64];  // [kv][64d], 16B chunks XOR-swizzled
  __shared__ __align__(16) short VT[64*40];  // V^T [d][kv], row stride 40 (pad 8)
  const int tid  = threadIdx.x;
  const int lane = tid & 63;
  const int wv   = tid >> 6;
  const int head = blockIdx.y;
  const int q0   = blockIdx.x*64 + wv*32;
  const int ql   = lane & 31;
  const int hi   = lane >> 5;
  const float scale = 0.125f;

  // Q fragments (registers): B-frag for S^T: col=q=ql, k=d = dc*16 + hi*8 + j
  short8 qf[4];
  {
    const __hip_bfloat16* qrow = QKV + (long)(q0+ql)*QKVN + head*HD + hi*8;
#pragma unroll
    for (int dc = 0; dc < 4; ++dc)
      qf[dc] = *(const short8*)(qrow + dc*16);
  }

  // K staging: LDS chunk (row, cs) holds global chunk cs^(row&7) (pre-swizzled src)
  const __hip_bfloat16* kp[2]; short* kl[2];
#pragma unroll
  for (int i = 0; i < 2; ++i) {
    int slot = i*128 + tid;
    int krow = slot >> 3, kcs = slot & 7;
    kp[i] = QKV + (long)krow*QKVN + HID + head*HD + ((kcs ^ (krow & 7))*8);
    kl[i] = Ks + (i*128 + wv*64)*8;
  }

  // V staging: thread handles V[kv=tid&31][dbase..dbase+15], writes transposed
  const int vkv = tid & 31, vdb = (tid >> 5) * 16;
  const __hip_bfloat16* vsrc = QKV + (long)vkv*QKVN + 2*HID + head*HD + vdb;

  f32x16 oacc[2] = {};
  float mrun = -1e30f, lrun = 0.0f;

  for (int kv0 = 0; kv0 < SEQ; kv0 += 32) {
    const long koff = (long)kv0 * QKVN;
    gload16(kp[0] + koff, kl[0]);
    gload16(kp[1] + koff, kl[1]);
    short8 v0 = *(const short8*)(vsrc + koff);
    short8 v1 = *(const short8*)(vsrc + koff + 8);
    float4 mg[4];
#pragma unroll
    for (int g = 0; g < 4; ++g)
      mg[g] = *(const float4*)(mask + kv0 + 8*g + 4*hi);
#pragma unroll
    for (int e = 0; e < 8; ++e) {
      VT[(vdb + e)*40 + vkv]     = v0[e];
      VT[(vdb + 8 + e)*40 + vkv] = v1[e];
    }
    __syncthreads();   // drains vmcnt (gload_lds) + lgkmcnt (VT writes)

    // K fragments: A-frag for S^T: row=kv=ql, k=d = dc*16 + hi*8 + j
    short8 kf[4];
#pragma unroll
    for (int dc = 0; dc < 4; ++dc)
      kf[dc] = *(const short8*)&Ks[ql*64 + (((dc*2 + hi) ^ (ql & 7))*8)];

    // S^T[kv][q] = K · Q^T
    f32x16 sacc = {};
#pragma unroll
    for (int dc = 0; dc < 4; ++dc)
      sacc = __builtin_amdgcn_mfma_f32_32x32x16_bf16(kf[dc], qf[dc], sacc, 0, 0, 0);

    // online softmax; lane's regs cover kv = (r&3) + 8*(r>>2) + 4*hi  (m74/m101 C/D map)
    float s[16], p[16];
#pragma unroll
    for (int g = 0; g < 4; ++g) {
      s[4*g+0] = sacc[4*g+0]*scale + mg[g].x;
      s[4*g+1] = sacc[4*g+1]*scale + mg[g].y;
      s[4*g+2] = sacc[4*g+2]*scale + mg[g].z;
      s[4*g+3] = sacc[4*g+3]*scale + mg[g].w;
    }
    float mloc = -1e30f;
#pragma unroll
    for (int r = 0; r < 16; ++r) mloc = fmaxf(mloc, s[r]);
    mloc = fmaxf(mloc, __shfl_xor(mloc, 32));
    float mnew = fmaxf(mrun, mloc);
    float corr = __expf(mrun - mnew);
    float sl = 0.f;
#pragma unroll
    for (int r = 0; r < 16; ++r) { p[r] = __expf(s[r] - mnew); sl += p[r]; }
    sl += __shfl_xor(sl, 32);
    lrun = lrun * corr + sl;
    mrun = mnew;
#pragma unroll
    for (int e = 0; e < 16; ++e) { oacc[0][e] *= corr; oacc[1][e] *= corr; }

    // P^T -> bf16 B-fragments (pack + half-exchange across lane^32)
    unsigned pk[8], pr[8];
#pragma unroll
    for (int u = 0; u < 8; ++u) pk[u] = pkbf(p[2*u], p[2*u+1]);
#pragma unroll
    for (int u = 0; u < 8; ++u) pr[u] = (unsigned)__shfl_xor((int)pk[u], 32);
    unsigned b0[4], b1[4];
    b0[0] = hi ? pr[2] : pk[0];  b0[1] = hi ? pr[3] : pk[1];
    b0[2] = hi ? pk[2] : pr[0];  b0[3] = hi ? pk[3] : pr[1];
    b1[0] = hi ? pr[6] : pk[4];  b1[1] = hi ? pr[7] : pk[5];
    b1[2] = hi ? pk[6] : pr[4];  b1[3] = hi ? pk[7] : pr[5];
    union U { unsigned u[4]; short8 s; };
    U pb0{{b0[0], b0[1], b0[2], b0[3]}};   // P^T[kv 0..15][q]
    U pb1{{b1[0], b1[1], b1[2], b1[3]}};   // P^T[kv 16..31][q]

    // V^T A-frags: row = d = cb*32 + ql, k = kv = (half)*16 + hi*8 + j
    short8 a00 = *(const short8*)&VT[(ql)*40      + hi*8];
    short8 a01 = *(const short8*)&VT[(ql)*40 + 16 + hi*8];
    short8 a10 = *(const short8*)&VT[(32+ql)*40      + hi*8];
    short8 a11 = *(const short8*)&VT[(32+ql)*40 + 16 + hi*8];

    oacc[0] = __builtin_amdgcn_mfma_f32_32x32x16_bf16(a00, pb0.s, oacc[0], 0, 0, 0);
    oacc[0] = __builtin_amdgcn_mfma_f32_32x32x16_bf16(a01, pb1.s, oacc[0], 0, 0, 0);
    oacc[1] = __builtin_amdgcn_mfma_f32_32x32x16_bf16(a10, pb0.s, oacc[1], 0, 0, 0);
    oacc[1] = __builtin_amdgcn_mfma_f32_32x32x16_bf16(a11, pb1.s, oacc[1], 0, 0, 0);
    __syncthreads();   // all LDS reads done -> safe to restage next tile
  }

  // epilogue: lane owns q = q0+ql; d = cb*32 + 8g + 4hi + r
  float inv = 1.0f / lrun;
  __hip_bfloat16* crow = ctx + (long)(q0+ql)*HID + head*HD;
#pragma unroll
  for (int cb = 0; cb < 2; ++cb)
#pragma unroll
    for (int g = 0; g < 4; ++g)
      store4(crow + cb*32 + 8*g + 4*hi,
             oacc[cb][4*g+0]*inv, oacc[cb][4*g+1]*inv,
             oacc[cb][4*g+2]*inv, oacc[cb][4*g+3]*inv);
}

// ---------------- launcher ----------------------------------------------------
extern "C" void kernel_launch(void* const* d_in, const int* in_sizes, int n_in,
                              void* d_out, int out_size, void* d_ws, size_t ws_size,
                              hipStream_t stream) {
  const float* hs  = (const float*)d_in[0];
  const float* msk = (const float*)d_in[1];
  const float* qw  = (const float*)d_in[2];
  const float* qb  = (const float*)d_in[3];
  const float* kw  = (const float*)d_in[4];
  const float* kb  = (const float*)d_in[5];
  const float* vw  = (const float*)d_in[6];
  const float* vb  = (const float*)d_in[7];
  const float* ow  = (const float*)d_in[8];
  const float* ob  = (const float*)d_in[9];

  char* ws = (char*)d_ws;
  __hip_bfloat16* Xb   = (__hip_bfloat16*)(ws);                 // 6,291,456 B
  __hip_bfloat16* Wqkv = (__hip_bfloat16*)(ws + 6291456);       // 3,538,944 B
  __hip_bfloat16* Wo   = (__hip_bfloat16*)(ws + 9830400);       // 1,179,648 B
  float*          bqkv = (float*)         (ws + 11010048);      //     9,216 B
  __hip_bfloat16* QKV  = (__hip_bfloat16*)(ws + 11019264);      // 18,874,368 B
  __hip_bfloat16* Ctx  = (__hip_bfloat16*)(ws + 29893632);      // 6,291,456 B

  {
    const int total = SEQ*HID/4 + QKVN*HID/4 + HID*HID/4 + QKVN/4;
    prep_kernel<<<(total + 255)/256, 256, 0, stream>>>(hs, qw, kw, vw, ow, qb, kb, vb,
                                                       Xb, Wqkv, Wo, bqkv);
  }
  gemm_nt<__hip_bfloat16><<<dim3(QKVN/128, SEQ/128), 256, 0, stream>>>(Xb, Wqkv, bqkv, QKV, QKVN, HID);
  attn_fwd<<<dim3(SEQ/64, NH), 128, 0, stream>>>(QKV, msk, Ctx);
  gemm_nt<float><<<dim3(HID/128, SEQ/128), 256, 0, stream>>>(Ctx, Wo, ob, (float*)d_out, HID, HID);
}